// Round 5
// baseline (404.972 us; speedup 1.0000x reference)
//
#include <hip/hip_runtime.h>
#include <hip/hip_bf16.h>
#include <cstdint>
#include <cstddef>

// Problem constants (reference: T=4096, C=2048, NE=2048)
#define T_LEN   4096
#define C_DIM   2048
#define NE_DIM  2048
#define CHUNK   32
#define NCHUNK  (T_LEN / CHUNK)   // 128
#define C2      (C_DIM / 2)       // 1024 float2 channels

typedef __bf16 bf16;
typedef __attribute__((ext_vector_type(8))) __bf16 bf16x8;
typedef __attribute__((ext_vector_type(4))) __bf16 bf16x4;
typedef __attribute__((ext_vector_type(2))) __bf16 bf16x2;
typedef __attribute__((ext_vector_type(4))) float  f32x4;

// ---------------------------------------------------------------------------
// async global->LDS, 16B per lane (dest is wave-uniform base + lane*16)
__device__ __forceinline__ void gld_lds16(bf16* lds_dst, const bf16* g_src) {
  __builtin_amdgcn_global_load_lds(
      (__attribute__((address_space(1))) void*)(g_src),
      (__attribute__((address_space(3))) void*)(lds_dst),
      16, 0, 0);
}

// ---------------------------------------------------------------------------
// Fused time-shift + mix: xk/xv/xr = x*m + shift(x)*(1-m), cast to bf16.
__global__ __launch_bounds__(256) void mix_kernel(
    const float* __restrict__ x,
    const float* __restrict__ tmk, const float* __restrict__ tmv,
    const float* __restrict__ tmr,
    bf16* __restrict__ xk, bf16* __restrict__ xv, bf16* __restrict__ xr)
{
  int gid = blockIdx.x * 256 + threadIdx.x;          // over T*NE/4
  int row = gid / (NE_DIM / 4);
  int e4  = gid % (NE_DIM / 4);
  const f32x4* x4 = (const f32x4*)x;
  f32x4 zero = {0.f, 0.f, 0.f, 0.f};
  f32x4 xc = x4[gid];
  f32x4 xp = (row > 0) ? x4[gid - NE_DIM / 4] : zero;
  f32x4 mk = ((const f32x4*)tmk)[e4];
  f32x4 mv = ((const f32x4*)tmv)[e4];
  f32x4 mr = ((const f32x4*)tmr)[e4];
  f32x4 vk = xc * mk + xp * (1.0f - mk);
  f32x4 vv = xc * mv + xp * (1.0f - mv);
  f32x4 vr = xc * mr + xp * (1.0f - mr);
  bf16x4 ok, ov, orr;
#pragma unroll
  for (int i = 0; i < 4; ++i) {
    ok[i]  = (bf16)vk[i];
    ov[i]  = (bf16)vv[i];
    orr[i] = (bf16)vr[i];
  }
  *(bf16x4*)(xk + (size_t)gid * 4) = ok;
  *(bf16x4*)(xv + (size_t)gid * 4) = ov;
  *(bf16x4*)(xr + (size_t)gid * 4) = orr;
}

// ---------------------------------------------------------------------------
// Transpose [2048x2048] f32 -> bf16 [N][K] (B^T layout for the GEMM).
__global__ __launch_bounds__(256) void wtrans(
    const float* __restrict__ W0, const float* __restrict__ W1,
    const float* __restrict__ W2, const float* __restrict__ W3,
    bf16* __restrict__ O0, bf16* __restrict__ O1,
    bf16* __restrict__ O2, bf16* __restrict__ O3)
{
  __shared__ float tile[32][33];
  int z = blockIdx.z;
  const float* W = (z == 0) ? W0 : (z == 1) ? W1 : (z == 2) ? W2 : W3;
  bf16* O        = (z == 0) ? O0 : (z == 1) ? O1 : (z == 2) ? O2 : O3;
  int bx = blockIdx.x * 32, by = blockIdx.y * 32;
  int tx = threadIdx.x, ty = threadIdx.y;
#pragma unroll
  for (int j = 0; j < 4; ++j)
    tile[ty + j * 8][tx] = W[(size_t)(by + ty + j * 8) * NE_DIM + bx + tx];
  __syncthreads();
#pragma unroll
  for (int j = 0; j < 4; ++j)
    O[(size_t)(bx + ty + j * 8) * NE_DIM + by + tx] = (bf16)tile[tx][ty + j * 8];
}

// ---------------------------------------------------------------------------
// Occupancy-first pipelined bf16 GEMM: C[4096,2048] = A @ Bt^T.
// BM=BN=128, BK=64, 256 thr (4 waves 2x2, 64x64 out each), LDS 64KB exactly
// -> 2 blocks/CU co-resident (cross-block fills barrier stalls).
// T1 XCD swizzle + T2 LDS XOR swizzle + counted vmcnt(8) (never drain to 0
// in the main loop) + setprio around the 32-MFMA cluster.
// Triple-GEMM fusion: blockIdx.y in {0,1,2} selects (A,Bt,C).
#define GK  2048
#define NT2 (GK / 64)          // 32 K-tiles

#define BARS() asm volatile("s_barrier" ::: "memory")
#define VMC(n) asm volatile("s_waitcnt vmcnt(" #n ")" ::: "memory")

// Stage one 128x64 A-tile and B-tile into buffer b (8 gld_lds, linear dest;
// global src column pre-swizzled so swizzled ds_read sees linear data).
#define STG(b, kt) do { \
  _Pragma("unroll") \
  for (int q = 0; q < 4; ++q) { \
    gld_lds16(&As[(b) * 8192 + q * 2048 + tid * 8], Ab + (size_t)(q * 32) * GK + (size_t)(kt) * 64); \
    gld_lds16(&Bs[(b) * 8192 + q * 2048 + tid * 8], Bb + (size_t)(q * 32) * GK + (size_t)(kt) * 64); \
  } \
} while (0)

#define COMPUTE(b) do { \
  bf16x8 af[4][2], bq[4][2]; \
  _Pragma("unroll") \
  for (int f = 0; f < 4; ++f) { \
    af[f][0] = *(const bf16x8*)&As[(b) * 8192 + aoff[f] + cx0]; \
    af[f][1] = *(const bf16x8*)&As[(b) * 8192 + aoff[f] + cx1]; \
    bq[f][0] = *(const bf16x8*)&Bs[(b) * 8192 + boff[f] + cx0]; \
    bq[f][1] = *(const bf16x8*)&Bs[(b) * 8192 + boff[f] + cx1]; \
  } \
  __builtin_amdgcn_s_setprio(1); \
  _Pragma("unroll") \
  for (int f = 0; f < 4; ++f) \
    _Pragma("unroll") \
    for (int g = 0; g < 4; ++g) { \
      acc[f][g] = __builtin_amdgcn_mfma_f32_16x16x32_bf16(af[f][0], bq[g][0], acc[f][g], 0, 0, 0); \
      acc[f][g] = __builtin_amdgcn_mfma_f32_16x16x32_bf16(af[f][1], bq[g][1], acc[f][g], 0, 0, 0); \
    } \
  __builtin_amdgcn_s_setprio(0); \
} while (0)

__global__ __launch_bounds__(256, 2) void gemm2(
    const bf16* __restrict__ A0p, const bf16* __restrict__ Bt0, float* __restrict__ C0p,
    const bf16* __restrict__ A1p, const bf16* __restrict__ Bt1, float* __restrict__ C1p,
    const bf16* __restrict__ A2p, const bf16* __restrict__ Bt2, float* __restrict__ C2p)
{
  __shared__ __align__(16) bf16 As[16384];   // 2 bufs x 128x64
  __shared__ __align__(16) bf16 Bs[16384];   // 2 bufs x 128x64  (64 KiB total)
  const int z = blockIdx.y;
  const bf16* A  = (z == 0) ? A0p : (z == 1) ? A1p : A2p;
  const bf16* Bt = (z == 0) ? Bt0 : (z == 1) ? Bt1 : Bt2;
  float*      C  = (z == 0) ? C0p : (z == 1) ? C1p : C2p;

  const int tid  = threadIdx.x;
  const int lane = tid & 63, w = tid >> 6;
  const int wm = w >> 1, wn = w & 1;         // 2x2 wave grid, 64x64 each
  const int lr = lane & 15, kb = lane >> 4;

  // T1: XCD swizzle (512 blocks, 512%8==0): XCD x owns bn in {2x, 2x+1}.
  int wg = blockIdx.x;
  int l  = (wg & 7) * 64 + (wg >> 3);
  int bm = l & 31, bn = l >> 5;              // M/128=32, N/128=16

  // staging map: 8 threads per 128B row, T2-swizzled 16B chunk
  const int sr = tid >> 3;                   // 0..31
  const int sc = (tid & 7) ^ (sr & 7);       // involution
  const bf16* Ab = A  + ((size_t)(bm * 128) + sr) * GK + sc * 8;
  const bf16* Bb = Bt + ((size_t)(bn * 128) + sr) * GK + sc * 8;

  // fragment read addressing (read side of same swizzle)
  const int cx0 = (kb ^ (lr & 7)) * 8;
  const int cx1 = ((kb ^ (lr & 7)) ^ 4) * 8;
  int aoff[4], boff[4];
#pragma unroll
  for (int f = 0; f < 4; ++f) {
    aoff[f] = (wm * 64 + f * 16 + lr) * 64;
    boff[f] = (wn * 64 + f * 16 + lr) * 64;
  }

  f32x4 acc[4][4] = {};

  STG(0, 0);                                 // prologue: tile0, 8 in flight
  for (int t = 0; t < NT2 - 1; ++t) {
    const int cur = t & 1;
    STG(cur ^ 1, t + 1);                     // prefetch next tile (8 more)
    VMC(8);                                  // drain tile t only
    BARS();
    COMPUTE(cur);
    BARS();
  }
  VMC(0);
  BARS();
  COMPUTE((NT2 - 1) & 1);

  // C-write: row = bm*128 + wm*64 + f*16 + kb*4 + j ; col = bn*128 + wn*64 + g*16 + lr
#pragma unroll
  for (int f = 0; f < 4; ++f)
#pragma unroll
    for (int g = 0; g < 4; ++g) {
      size_t r0 = (size_t)(bm * 128) + wm * 64 + f * 16 + kb * 4;
      int    c0 = bn * 128 + wn * 64 + g * 16 + lr;
#pragma unroll
      for (int j = 0; j < 4; ++j)
        C[(r0 + j) * C_DIM + c0] = acc[f][g][j];
    }
}

// ---------------------------------------------------------------------------
// WKV chunked scan (CHUNK=32, float2-vectorized channels).
// Per channel: f = exp(-exp(td)); per-step decay D = exp(-f);
// A' = D*A + e^k v ; B' = D*B + e^k ; wkv = (A + e^{u+k} v)/(B + e^{u+k}).
__global__ __launch_bounds__(256) void wkv_phase1(
    const float2* __restrict__ k2, const float2* __restrict__ v2,
    const float2* __restrict__ td2,
    float2* __restrict__ SA, float2* __restrict__ SB)
{
  int c = blockIdx.x * 256 + threadIdx.x;    // float2 channel 0..1023
  int m = blockIdx.y;
  float2 td = td2[c];
  float fx = __expf(-__expf(td.x)), fy = __expf(-__expf(td.y));
  float Dx = __expf(-fx), Dy = __expf(-fy);
  float sax = 0.f, say = 0.f, sbx = 0.f, sby = 0.f;
  size_t base = (size_t)m * CHUNK * C2 + c;
  for (int t = 0; t < CHUNK; ++t) {
    float2 kk = k2[base + (size_t)t * C2];
    float2 vv = v2[base + (size_t)t * C2];
    float ekx = __expf(kk.x), eky = __expf(kk.y);
    sax = Dx * sax + ekx * vv.x;  sbx = Dx * sbx + ekx;
    say = Dy * say + eky * vv.y;  sby = Dy * sby + eky;
  }
  SA[(size_t)m * C2 + c] = make_float2(sax, say);
  SB[(size_t)m * C2 + c] = make_float2(sbx, sby);
}

__global__ __launch_bounds__(256) void wkv_phase2(
    const float2* __restrict__ td2,
    const float2* __restrict__ SA, const float2* __restrict__ SB,
    float2* __restrict__ A0, float2* __restrict__ B0)
{
  int c = blockIdx.x * 256 + threadIdx.x;
  float2 td = td2[c];
  float fx = __expf(-__expf(td.x)), fy = __expf(-__expf(td.y));
  float DLx = __expf(-fx * (float)CHUNK), DLy = __expf(-fy * (float)CHUNK);
  float ax = 0.f, ay = 0.f, bx = 0.f, by = 0.f;
  for (int m = 0; m < NCHUNK; ++m) {
    A0[(size_t)m * C2 + c] = make_float2(ax, ay);
    B0[(size_t)m * C2 + c] = make_float2(bx, by);
    float2 sa = SA[(size_t)m * C2 + c];
    float2 sb = SB[(size_t)m * C2 + c];
    ax = DLx * ax + sa.x;  ay = DLy * ay + sa.y;
    bx = DLx * bx + sb.x;  by = DLy * by + sb.y;
  }
}

__global__ __launch_bounds__(256) void wkv_phase3(
    const float2* __restrict__ k2, const float2* __restrict__ v2,
    const float2* __restrict__ r2,
    const float2* __restrict__ td2, const float2* __restrict__ tf2,
    const float2* __restrict__ A0, const float2* __restrict__ B0,
    bf16* __restrict__ y)
{
  int c = blockIdx.x * 256 + threadIdx.x;
  int m = blockIdx.y;
  float2 td = td2[c], tf = tf2[c];
  float fx = __expf(-__expf(td.x)), fy = __expf(-__expf(td.y));
  float Dx = __expf(-fx), Dy = __expf(-fy);
  float eux = __expf(tf.x), euy = __expf(tf.y);
  float2 a0 = A0[(size_t)m * C2 + c], b0 = B0[(size_t)m * C2 + c];
  float ax = a0.x, ay = a0.y, bx = b0.x, by = b0.y;
  size_t base = (size_t)m * CHUNK * C2 + c;
  for (int t = 0; t < CHUNK; ++t) {
    size_t idx = base + (size_t)t * C2;
    float2 kk = k2[idx], vv = v2[idx], rr = r2[idx];
    float ekx = __expf(kk.x), eky = __expf(kk.y);
    float ex = eux * ekx,     ey = euy * eky;
    float wx = (ax + ex * vv.x) / (bx + ex);
    float wy = (ay + ey * vv.y) / (by + ey);
    float sx = 1.0f / (1.0f + __expf(-rr.x));
    float sy = 1.0f / (1.0f + __expf(-rr.y));
    bf16x2 o2; o2[0] = (bf16)(sx * wx); o2[1] = (bf16)(sy * wy);
    *(bf16x2*)&y[idx * 2] = o2;
    ax = Dx * ax + ekx * vv.x;  bx = Dx * bx + ekx;
    ay = Dy * ay + eky * vv.y;  by = Dy * by + eky;
  }
}

// ---------------------------------------------------------------------------
extern "C" void kernel_launch(void* const* d_in, const int* in_sizes, int n_in,
                              void* d_out, int out_size, void* d_ws, size_t ws_size,
                              hipStream_t stream)
{
  (void)in_sizes; (void)n_in; (void)out_size; (void)ws_size;
  const float* x   = (const float*)d_in[0];
  const float* tf  = (const float*)d_in[1];
  const float* td  = (const float*)d_in[2];
  const float* tmk = (const float*)d_in[3];
  const float* tmv = (const float*)d_in[4];
  const float* tmr = (const float*)d_in[5];
  const float* Wk  = (const float*)d_in[6];
  const float* Wv  = (const float*)d_in[7];
  const float* Wr  = (const float*)d_in[8];
  const float* Wo  = (const float*)d_in[9];
  float* out = (float*)d_out;

  char* ws = (char*)d_ws;
  size_t off = 0;
  auto alloc = [&](size_t bytes) {
    void* p = ws + off;
    off += (bytes + 255) & ~(size_t)255;
    return p;
  };
  const size_t TN  = (size_t)T_LEN * NE_DIM;   // 8,388,608
  const size_t WN  = (size_t)C_DIM * NE_DIM;   // 4,194,304

  bf16* xk   = (bf16*)alloc(TN * 2);
  bf16* xv   = (bf16*)alloc(TN * 2);
  bf16* xr   = (bf16*)alloc(TN * 2);
  bf16* WkT  = (bf16*)alloc(WN * 2);
  bf16* WvT  = (bf16*)alloc(WN * 2);
  bf16* WrT  = (bf16*)alloc(WN * 2);
  bf16* WoT  = (bf16*)alloc(WN * 2);
  float* kbuf = (float*)alloc(TN * 4);
  float* vbuf = (float*)alloc(TN * 4);
  float* rbuf = (float*)alloc(TN * 4);
  // Aliases into dead regions (stream-ordered; xk/xv dead after the k/v/r GEMMs):
  bf16*   y  = xk;                             // [T,C] bf16
  float2* SA = (float2*)xv;                    // 4 x 1MB into xv's 16.8MB
  float2* SB = SA + (size_t)NCHUNK * C2;
  float2* A0 = SB + (size_t)NCHUNK * C2;
  float2* B0 = A0 + (size_t)NCHUNK * C2;

  // 1. mix + bf16 cast
  mix_kernel<<<dim3((unsigned)(TN / 4 / 256)), 256, 0, stream>>>(
      x, tmk, tmv, tmr, xk, xv, xr);
  // 2. weight transpose + bf16 cast
  wtrans<<<dim3(64, 64, 4), dim3(32, 8), 0, stream>>>(
      Wk, Wv, Wr, Wo, WkT, WvT, WrT, WoT);
  // 3. k/v/r projections fused in one dispatch (grid 512 x 3, 2 blocks/CU)
  gemm2<<<dim3(512, 3), 256, 0, stream>>>(
      xk, WkT, kbuf, xv, WvT, vbuf, xr, WrT, rbuf);
  // 4. WKV chunked scan + sigmoid fuse -> y (bf16)
  wkv_phase1<<<dim3(C2 / 256, NCHUNK), 256, 0, stream>>>(
      (const float2*)kbuf, (const float2*)vbuf, (const float2*)td, SA, SB);
  wkv_phase2<<<dim3(C2 / 256), 256, 0, stream>>>(
      (const float2*)td, SA, SB, A0, B0);
  wkv_phase3<<<dim3(C2 / 256, NCHUNK), 256, 0, stream>>>(
      (const float2*)kbuf, (const float2*)vbuf, (const float2*)rbuf,
      (const float2*)td, (const float2*)tf, A0, B0, y);
  // 5. output projection
  gemm2<<<dim3(512, 1), 256, 0, stream>>>(
      y, WoT, out, y, WoT, out, y, WoT, out);
}

// Round 6
// 379.584 us; speedup vs baseline: 1.0669x; 1.0669x over previous
//
#include <hip/hip_runtime.h>
#include <hip/hip_bf16.h>
#include <cstdint>
#include <cstddef>

// Problem constants (reference: T=4096, C=2048, NE=2048)
#define T_LEN   4096
#define C_DIM   2048
#define NE_DIM  2048
#define CHUNK   32
#define NCHUNK  (T_LEN / CHUNK)   // 128
#define C2      (C_DIM / 2)       // 1024 float2 channels

typedef __bf16 bf16;
typedef __attribute__((ext_vector_type(8))) __bf16 bf16x8;
typedef __attribute__((ext_vector_type(4))) __bf16 bf16x4;
typedef __attribute__((ext_vector_type(2))) __bf16 bf16x2;
typedef __attribute__((ext_vector_type(4))) float  f32x4;

// ---------------------------------------------------------------------------
// async global->LDS, 16B per lane (dest is wave-uniform base + lane*16)
__device__ __forceinline__ void gld_lds16(bf16* lds_dst, const bf16* g_src) {
  __builtin_amdgcn_global_load_lds(
      (__attribute__((address_space(1))) void*)(g_src),
      (__attribute__((address_space(3))) void*)(lds_dst),
      16, 0, 0);
}

// ---------------------------------------------------------------------------
// Fused time-shift + mix: xk/xv/xr = x*m + shift(x)*(1-m), cast to bf16.
__global__ __launch_bounds__(256) void mix_kernel(
    const float* __restrict__ x,
    const float* __restrict__ tmk, const float* __restrict__ tmv,
    const float* __restrict__ tmr,
    bf16* __restrict__ xk, bf16* __restrict__ xv, bf16* __restrict__ xr)
{
  int gid = blockIdx.x * 256 + threadIdx.x;          // over T*NE/4
  int row = gid / (NE_DIM / 4);
  int e4  = gid % (NE_DIM / 4);
  const f32x4* x4 = (const f32x4*)x;
  f32x4 zero = {0.f, 0.f, 0.f, 0.f};
  f32x4 xc = x4[gid];
  f32x4 xp = (row > 0) ? x4[gid - NE_DIM / 4] : zero;
  f32x4 mk = ((const f32x4*)tmk)[e4];
  f32x4 mv = ((const f32x4*)tmv)[e4];
  f32x4 mr = ((const f32x4*)tmr)[e4];
  f32x4 vk = xc * mk + xp * (1.0f - mk);
  f32x4 vv = xc * mv + xp * (1.0f - mv);
  f32x4 vr = xc * mr + xp * (1.0f - mr);
  bf16x4 ok, ov, orr;
#pragma unroll
  for (int i = 0; i < 4; ++i) {
    ok[i]  = (bf16)vk[i];
    ov[i]  = (bf16)vv[i];
    orr[i] = (bf16)vr[i];
  }
  *(bf16x4*)(xk + (size_t)gid * 4) = ok;
  *(bf16x4*)(xv + (size_t)gid * 4) = ov;
  *(bf16x4*)(xr + (size_t)gid * 4) = orr;
}

// ---------------------------------------------------------------------------
// Transpose [2048x2048] f32 -> bf16 [N][K] (B^T layout for the GEMM).
__global__ __launch_bounds__(256) void wtrans(
    const float* __restrict__ W0, const float* __restrict__ W1,
    const float* __restrict__ W2, const float* __restrict__ W3,
    bf16* __restrict__ O0, bf16* __restrict__ O1,
    bf16* __restrict__ O2, bf16* __restrict__ O3)
{
  __shared__ float tile[32][33];
  int z = blockIdx.z;
  const float* W = (z == 0) ? W0 : (z == 1) ? W1 : (z == 2) ? W2 : W3;
  bf16* O        = (z == 0) ? O0 : (z == 1) ? O1 : (z == 2) ? O2 : O3;
  int bx = blockIdx.x * 32, by = blockIdx.y * 32;
  int tx = threadIdx.x, ty = threadIdx.y;
#pragma unroll
  for (int j = 0; j < 4; ++j)
    tile[ty + j * 8][tx] = W[(size_t)(by + ty + j * 8) * NE_DIM + bx + tx];
  __syncthreads();
#pragma unroll
  for (int j = 0; j < 4; ++j)
    O[(size_t)(bx + ty + j * 8) * NE_DIM + by + tx] = (bf16)tile[tx][ty + j * 8];
}

// ---------------------------------------------------------------------------
// Deep-ring pipelined bf16 GEMM: C[4096,2048] = A @ Bt^T.
// BM=BN=128, BK=32, 256 thr (4 waves 2x2, 64x64 out each), 3-buffer ring
// (48KB LDS -> 3 blocks/CU), prefetch 2 K-tiles ahead, vmcnt(8) steady state.
// Swizzle (64B rows, 4x16B chunks): stage chunk gc=(tid&3)^((tid>>3)&3),
// read chunk kb^((lr>>1)&3) -> worst-case 2-way bank aliasing (free).
// Triple-GEMM fusion: blockIdx.y in {0,1,2}.
#define GK  2048
#define NT3 (GK / 32)          // 64 K-tiles

#define BARS() asm volatile("s_barrier" ::: "memory")
#define VMC(n) asm volatile("s_waitcnt vmcnt(" #n ")" ::: "memory")

// Stage one 128x32 A-tile and B-tile into buffer at elem-offset boff.
// Ab/Bb already include srow*GK + gc*8.
#define STG(boff, kt) do { \
  gld_lds16(&As[(boff) + tid * 8],        Ab + (size_t)(kt) * 32); \
  gld_lds16(&As[(boff) + 2048 + tid * 8], Ab + (size_t)64 * GK + (size_t)(kt) * 32); \
  gld_lds16(&Bs[(boff) + tid * 8],        Bb + (size_t)(kt) * 32); \
  gld_lds16(&Bs[(boff) + 2048 + tid * 8], Bb + (size_t)64 * GK + (size_t)(kt) * 32); \
} while (0)

#define COMPUTE(boff) do { \
  bf16x8 af[4], bq[4]; \
  _Pragma("unroll") \
  for (int f = 0; f < 4; ++f) { \
    af[f] = *(const bf16x8*)&As[(boff) + aoff[f]]; \
    bq[f] = *(const bf16x8*)&Bs[(boff) + bqo[f]]; \
  } \
  __builtin_amdgcn_s_setprio(1); \
  _Pragma("unroll") \
  for (int f = 0; f < 4; ++f) \
    _Pragma("unroll") \
    for (int g = 0; g < 4; ++g) \
      acc[f][g] = __builtin_amdgcn_mfma_f32_16x16x32_bf16(af[f], bq[g], acc[f][g], 0, 0, 0); \
  __builtin_amdgcn_s_setprio(0); \
} while (0)

__global__ __launch_bounds__(256, 3) void gemm3(
    const bf16* __restrict__ A0p, const bf16* __restrict__ Bt0, float* __restrict__ C0p,
    const bf16* __restrict__ A1p, const bf16* __restrict__ Bt1, float* __restrict__ C1p,
    const bf16* __restrict__ A2p, const bf16* __restrict__ Bt2, float* __restrict__ C2p)
{
  __shared__ __align__(16) bf16 As[12288];   // 3 bufs x 128x32 (24 KiB)
  __shared__ __align__(16) bf16 Bs[12288];   // 3 bufs x 128x32 (24 KiB)
  const int z = blockIdx.y;
  const bf16* A  = (z == 0) ? A0p : (z == 1) ? A1p : A2p;
  const bf16* Bt = (z == 0) ? Bt0 : (z == 1) ? Bt1 : Bt2;
  float*      C  = (z == 0) ? C0p : (z == 1) ? C1p : C2p;

  const int tid  = threadIdx.x;
  const int lane = tid & 63, w = tid >> 6;
  const int wm = w >> 1, wn = w & 1;         // 2x2 wave grid, 64x64 each
  const int lr = lane & 15, kb = lane >> 4;

  // T1: XCD swizzle (512 blocks, 512%8==0): XCD x owns bn in {2x, 2x+1}.
  int wg = blockIdx.x;
  int l  = (wg & 7) * 64 + (wg >> 3);
  int bm = l & 31, bn = l >> 5;              // M/128=32, N/128=16

  // staging map: 4 threads per 64B row, T2-swizzled 16B chunk
  const int srow = tid >> 2;                 // 0..63
  const int gc   = (tid & 3) ^ ((tid >> 3) & 3);   // involution
  const bf16* Ab = A  + ((size_t)(bm * 128) + srow) * GK + gc * 8;
  const bf16* Bb = Bt + ((size_t)(bn * 128) + srow) * GK + gc * 8;

  // fragment read addressing (read side of same swizzle)
  const int cxp = (kb ^ ((lr >> 1) & 3)) * 8;
  int aoff[4], bqo[4];
#pragma unroll
  for (int f = 0; f < 4; ++f) {
    aoff[f] = (wm * 64 + f * 16 + lr) * 32 + cxp;
    bqo[f]  = (wn * 64 + f * 16 + lr) * 32 + cxp;
  }

  f32x4 acc[4][4] = {};

  STG(0, 0); STG(4096, 1);                   // prologue: 8 in flight
  int b0 = 0, b1 = 4096, b2 = 8192;          // elem offsets, rotating ring
  for (int t = 0; t < NT3 - 2; ++t) {
    STG(b2, t + 2);                          // 12 in flight
    VMC(8);                                  // tile t's 4 landed
    BARS();
    COMPUTE(b0);
    BARS();
    int tmp = b0; b0 = b1; b1 = b2; b2 = tmp;
  }
  VMC(4); BARS(); COMPUTE(b0); BARS();       // tile NT3-2
  VMC(0); BARS(); COMPUTE(b1);               // tile NT3-1

  // C-write: row = bm*128 + wm*64 + f*16 + kb*4 + j ; col = bn*128 + wn*64 + g*16 + lr
#pragma unroll
  for (int f = 0; f < 4; ++f)
#pragma unroll
    for (int g = 0; g < 4; ++g) {
      size_t r0 = (size_t)(bm * 128) + wm * 64 + f * 16 + kb * 4;
      int    c0 = bn * 128 + wn * 64 + g * 16 + lr;
#pragma unroll
      for (int j = 0; j < 4; ++j)
        C[(r0 + j) * C_DIM + c0] = acc[f][g][j];
    }
}

// ---------------------------------------------------------------------------
// WKV chunked scan (CHUNK=32, float2-vectorized channels).
// Per channel: f = exp(-exp(td)); per-step decay D = exp(-f);
// A' = D*A + e^k v ; B' = D*B + e^k ; wkv = (A + e^{u+k} v)/(B + e^{u+k}).
__global__ __launch_bounds__(256) void wkv_phase1(
    const float2* __restrict__ k2, const float2* __restrict__ v2,
    const float2* __restrict__ td2,
    float2* __restrict__ SA, float2* __restrict__ SB)
{
  int c = blockIdx.x * 256 + threadIdx.x;    // float2 channel 0..1023
  int m = blockIdx.y;
  float2 td = td2[c];
  float fx = __expf(-__expf(td.x)), fy = __expf(-__expf(td.y));
  float Dx = __expf(-fx), Dy = __expf(-fy);
  float sax = 0.f, say = 0.f, sbx = 0.f, sby = 0.f;
  size_t base = (size_t)m * CHUNK * C2 + c;
  for (int t = 0; t < CHUNK; ++t) {
    float2 kk = k2[base + (size_t)t * C2];
    float2 vv = v2[base + (size_t)t * C2];
    float ekx = __expf(kk.x), eky = __expf(kk.y);
    sax = Dx * sax + ekx * vv.x;  sbx = Dx * sbx + ekx;
    say = Dy * say + eky * vv.y;  sby = Dy * sby + eky;
  }
  SA[(size_t)m * C2 + c] = make_float2(sax, say);
  SB[(size_t)m * C2 + c] = make_float2(sbx, sby);
}

// Unrolled prefix over chunk states: loads of a group of 8 are independent
// and issue together (latency-bound before; ~8x fewer serial load latencies).
__global__ __launch_bounds__(256) void wkv_phase2(
    const float2* __restrict__ td2,
    const float2* __restrict__ SA, const float2* __restrict__ SB,
    float2* __restrict__ A0, float2* __restrict__ B0)
{
  int c = blockIdx.x * 256 + threadIdx.x;
  float2 td = td2[c];
  float fx = __expf(-__expf(td.x)), fy = __expf(-__expf(td.y));
  float DLx = __expf(-fx * (float)CHUNK), DLy = __expf(-fy * (float)CHUNK);
  float ax = 0.f, ay = 0.f, bx = 0.f, by = 0.f;
  for (int m0 = 0; m0 < NCHUNK; m0 += 8) {
    float2 sa[8], sb[8];
#pragma unroll
    for (int j = 0; j < 8; ++j) {
      sa[j] = SA[(size_t)(m0 + j) * C2 + c];
      sb[j] = SB[(size_t)(m0 + j) * C2 + c];
    }
#pragma unroll
    for (int j = 0; j < 8; ++j) {
      A0[(size_t)(m0 + j) * C2 + c] = make_float2(ax, ay);
      B0[(size_t)(m0 + j) * C2 + c] = make_float2(bx, by);
      ax = DLx * ax + sa[j].x;  ay = DLy * ay + sa[j].y;
      bx = DLx * bx + sb[j].x;  by = DLy * by + sb[j].y;
    }
  }
}

__global__ __launch_bounds__(256) void wkv_phase3(
    const float2* __restrict__ k2, const float2* __restrict__ v2,
    const float2* __restrict__ r2,
    const float2* __restrict__ td2, const float2* __restrict__ tf2,
    const float2* __restrict__ A0, const float2* __restrict__ B0,
    bf16* __restrict__ y)
{
  int c = blockIdx.x * 256 + threadIdx.x;
  int m = blockIdx.y;
  float2 td = td2[c], tf = tf2[c];
  float fx = __expf(-__expf(td.x)), fy = __expf(-__expf(td.y));
  float Dx = __expf(-fx), Dy = __expf(-fy);
  float eux = __expf(tf.x), euy = __expf(tf.y);
  float2 a0 = A0[(size_t)m * C2 + c], b0 = B0[(size_t)m * C2 + c];
  float ax = a0.x, ay = a0.y, bx = b0.x, by = b0.y;
  size_t base = (size_t)m * CHUNK * C2 + c;
  for (int t = 0; t < CHUNK; ++t) {
    size_t idx = base + (size_t)t * C2;
    float2 kk = k2[idx], vv = v2[idx], rr = r2[idx];
    float ekx = __expf(kk.x), eky = __expf(kk.y);
    float ex = eux * ekx,     ey = euy * eky;
    float wx = (ax + ex * vv.x) / (bx + ex);
    float wy = (ay + ey * vv.y) / (by + ey);
    float sx = 1.0f / (1.0f + __expf(-rr.x));
    float sy = 1.0f / (1.0f + __expf(-rr.y));
    bf16x2 o2; o2[0] = (bf16)(sx * wx); o2[1] = (bf16)(sy * wy);
    *(bf16x2*)&y[idx * 2] = o2;
    ax = Dx * ax + ekx * vv.x;  bx = Dx * bx + ekx;
    ay = Dy * ay + eky * vv.y;  by = Dy * by + eky;
  }
}

// ---------------------------------------------------------------------------
extern "C" void kernel_launch(void* const* d_in, const int* in_sizes, int n_in,
                              void* d_out, int out_size, void* d_ws, size_t ws_size,
                              hipStream_t stream)
{
  (void)in_sizes; (void)n_in; (void)out_size; (void)ws_size;
  const float* x   = (const float*)d_in[0];
  const float* tf  = (const float*)d_in[1];
  const float* td  = (const float*)d_in[2];
  const float* tmk = (const float*)d_in[3];
  const float* tmv = (const float*)d_in[4];
  const float* tmr = (const float*)d_in[5];
  const float* Wk  = (const float*)d_in[6];
  const float* Wv  = (const float*)d_in[7];
  const float* Wr  = (const float*)d_in[8];
  const float* Wo  = (const float*)d_in[9];
  float* out = (float*)d_out;

  char* ws = (char*)d_ws;
  size_t off = 0;
  auto alloc = [&](size_t bytes) {
    void* p = ws + off;
    off += (bytes + 255) & ~(size_t)255;
    return p;
  };
  const size_t TN  = (size_t)T_LEN * NE_DIM;   // 8,388,608
  const size_t WN  = (size_t)C_DIM * NE_DIM;   // 4,194,304

  bf16* xk   = (bf16*)alloc(TN * 2);
  bf16* xv   = (bf16*)alloc(TN * 2);
  bf16* xr   = (bf16*)alloc(TN * 2);
  bf16* WkT  = (bf16*)alloc(WN * 2);
  bf16* WvT  = (bf16*)alloc(WN * 2);
  bf16* WrT  = (bf16*)alloc(WN * 2);
  bf16* WoT  = (bf16*)alloc(WN * 2);
  float* kbuf = (float*)alloc(TN * 4);
  float* vbuf = (float*)alloc(TN * 4);
  float* rbuf = (float*)alloc(TN * 4);
  // Aliases into dead regions (stream-ordered; xk/xv dead after the k/v/r GEMMs):
  bf16*   y  = xk;                             // [T,C] bf16
  float2* SA = (float2*)xv;                    // 4 x 1MB into xv's 16.8MB
  float2* SB = SA + (size_t)NCHUNK * C2;
  float2* A0 = SB + (size_t)NCHUNK * C2;
  float2* B0 = A0 + (size_t)NCHUNK * C2;

  // 1. mix + bf16 cast
  mix_kernel<<<dim3((unsigned)(TN / 4 / 256)), 256, 0, stream>>>(
      x, tmk, tmv, tmr, xk, xv, xr);
  // 2. weight transpose + bf16 cast
  wtrans<<<dim3(64, 64, 4), dim3(32, 8), 0, stream>>>(
      Wk, Wv, Wr, Wo, WkT, WvT, WrT, WoT);
  // 3. k/v/r projections fused in one dispatch (grid 512 x 3, 3 blocks/CU)
  gemm3<<<dim3(512, 3), 256, 0, stream>>>(
      xk, WkT, kbuf, xv, WvT, vbuf, xr, WrT, rbuf);
  // 4. WKV chunked scan + sigmoid fuse -> y (bf16)
  wkv_phase1<<<dim3(C2 / 256, NCHUNK), 256, 0, stream>>>(
      (const float2*)kbuf, (const float2*)vbuf, (const float2*)td, SA, SB);
  wkv_phase2<<<dim3(C2 / 256), 256, 0, stream>>>(
      (const float2*)td, SA, SB, A0, B0);
  wkv_phase3<<<dim3(C2 / 256, NCHUNK), 256, 0, stream>>>(
      (const float2*)kbuf, (const float2*)vbuf, (const float2*)rbuf,
      (const float2*)td, (const float2*)tf, A0, B0, y);
  // 5. output projection
  gemm3<<<dim3(512, 1), 256, 0, stream>>>(
      y, WoT, out, y, WoT, out, y, WoT, out);
}